// Round 12
// baseline (156.114 us; speedup 1.0000x reference)
//
#include <hip/hip_runtime.h>
#include <hip/hip_bf16.h>

// FrequencyLayer: separable real DFT via bf16 MFMA.
// real[b,c,u,v] = sum_{i,j} x[i,j] cos(2pi(j*u+i*v)/N)
// imag[b,c,u,v] = -sum_{i,j} x[i,j] sin(2pi(j*u+i*v)/N), N=256, u,v in [0,128)
//
// v12 = v11 (134us) + LDS-conflict fix + setprio:
//  - intermediate-region swizzle: sw = ((ul&7)<<4) ^ ((ul&8)<<1).
//    Phase C writes even rows only (ul=2*l15+p); old (ul&7)<<4 gave 4 bank
//    groups -> 4-way write conflict. New hash spreads even rows over all 8
//    groups (2-way = free); phase-D reads (consecutive ul) stay 2-way.
//    Applied to BOTH phase C (writer) and phase D (reader). Table region
//    (256B rows) unchanged.
//  - s_setprio(1) around B/D MFMA clusters (staggered waves = role diversity,
//    the T5 prerequisite).

typedef __attribute__((ext_vector_type(8))) short short8;   // 8 bf16 = 4 VGPR
typedef __attribute__((ext_vector_type(4))) short bf16x4;   // 4 bf16 = 8B
typedef __attribute__((ext_vector_type(4))) float f32x4;    // MFMA C/D frag
typedef __attribute__((ext_vector_type(2))) float f32x2;

typedef union { short8 s8; unsigned u[4]; } pk8;            // v9-proven pattern
typedef union { bf16x4 s4; unsigned u[2]; } pk4;

#define NN 256
#define KF 128
#define NIMG 1024

// unified parity tables, rows m=0..63 -> freq 2m (E) / 2m+1 (O); cols j=0..127
__device__ __align__(16) short gcE[64 * 128];
__device__ __align__(16) short gcO[64 * 128];
__device__ __align__(16) short gsE[64 * 128];
__device__ __align__(16) short gsO[64 * 128];
__device__ int g_tables_done = 0;

__device__ __forceinline__ short f2bf(float f) {
    union { float f; unsigned u; } v; v.f = f;
    unsigned r = v.u + 0x7FFFu + ((v.u >> 16) & 1u);  // RNE
    return (short)(r >> 16);
}

__device__ __forceinline__ unsigned cvtpk(float lo, float hi) {
    unsigned r;
    asm("v_cvt_pk_bf16_f32 %0, %1, %2" : "=v"(r) : "v"(lo), "v"(hi));
    return r;
}

__global__ void gen_tables() {
    if (g_tables_done) return;           // tables persist across iterations
    int tid = blockIdx.x * blockDim.x + threadIdx.x;
    if (tid < 64 * 128) {
        const float w = 0.02454369260617026f;            // 2pi/256
        int m = tid >> 7;
        int j = tid & 127;
        int pe = (j * (2 * m)) & 255;
        int po = (j * (2 * m + 1)) & 255;
        float se, ce, so, co;
        sincosf((float)pe * w, &se, &ce);
        sincosf((float)po * w, &so, &co);
        gcE[tid] = f2bf(ce);
        gcO[tid] = f2bf(co);
        gsE[tid] = f2bf(se);
        gsO[tid] = f2bf(so);
    }
    __threadfence();
    if (tid == 0) g_tables_done = 1;     // set AFTER writes are visible
}

#define MFMA(a, b, c) __builtin_amdgcn_mfma_f32_16x16x32_bf16(a, b, c, 0, 0, 0)
// swizzle for the 512B-row intermediate region (phase C writes / phase D reads)
#define SWZ(ul) ((((ul) & 7) << 4) ^ (((ul) & 8) << 1))

__global__ __launch_bounds__(512, 4) void freq_dft(const float* __restrict__ x,
                                                   float* __restrict__ out) {
    // LDS (64KB), two lifetimes:
    //   phase A/B: Ctab [64][128] bf16 swz (16KB) @0 | Stab (-sin, 16KB) @16384
    //   phase C/D: eA|oA [64u][256k] (32KB) @0 | eBn|oBn (32KB) @32768
    __shared__ __align__(16) char lds[65536];

    // XCD-pairing decode: both h-half blocks of one image land on the same XCD.
    const int bid = blockIdx.x;
    const int cc  = bid & 7;
    const int q   = bid >> 3;
    const int h   = q & 1;
    const int img = cc + ((q >> 1) << 3);

    const float* __restrict__ X = x + (size_t)img * (NN * NN);
    float* __restrict__ outR = out + (size_t)img * (KF * KF);
    float* __restrict__ outI = outR + (size_t)NIMG * (KF * KF);

    const int lane = threadIdx.x & 63;
    const int wave = threadIdx.x >> 6;   // 0..7
    const int l15  = lane & 15;
    const int lk8  = (lane >> 4) << 3;   // A/B frag k-base (elems)
    const int lr4  = (lane >> 4) << 2;   // D frag row-base
    const int wst  = wave;               // stagger offset

    const short8 smask = {(short)0x8000, (short)0x8000, (short)0x8000, (short)0x8000,
                          (short)0x8000, (short)0x8000, (short)0x8000, (short)0x8000};

    // ---- HOISTED phase-B X prologue: issue before phase A (LDS-independent) -------
    const int i0 = wave * 16;
    const float* __restrict__ xL = X + (i0 + l15) * NN + lk8;        // iLo rows
    const float* __restrict__ xH = X + (i0 + 128 + l15) * NN + lk8;  // iHi rows
    const int jP = (wst & 3) * 32;
    f32x4 r0 = *(const f32x4*)(xL + jP),       r1 = *(const f32x4*)(xL + jP + 4);
    f32x4 r2 = *(const f32x4*)(xL + jP + 128), r3 = *(const f32x4*)(xL + jP + 132);
    f32x4 r4 = *(const f32x4*)(xH + jP),       r5 = *(const f32x4*)(xH + jP + 4);
    f32x4 r6 = *(const f32x4*)(xH + jP + 128), r7 = *(const f32x4*)(xH + jP + 132);

    // ---------------- phase A: parity tables -> LDS (swizzled; sin negated) --------
    {
        #pragma unroll
        for (int k = 0; k < 2; ++k) {      // Ctab: 1024 x 16B chunks
            int c   = threadIdx.x + k * 512;
            int row = c >> 4, chk = c & 15;
            int byte = row * 256 + ((chk << 4) ^ ((row & 7) << 4));
            const short* src = (row < 32 ? gcE + (h * 32 + row) * 128
                                         : gcO + (h * 32 + row - 32) * 128) + chk * 8;
            *(short8*)(lds + byte) = *(const short8*)src;
        }
        #pragma unroll
        for (int k = 0; k < 2; ++k) {      // Stab = -sin
            int c   = threadIdx.x + k * 512;
            int row = c >> 4, chk = c & 15;
            int byte = row * 256 + ((chk << 4) ^ ((row & 7) << 4));
            const short* src = (row < 32 ? gsE + (h * 32 + row) * 128
                                         : gsO + (h * 32 + row - 32) * 128) + chk * 8;
            short8 v = *(const short8*)src;
            *(short8*)(lds + 16384 + byte) = v ^ smask;
        }
    }
    __syncthreads();

    // ------- phase B: stage 1, K=128 j-folded, parity tables from LDS --------------
    f32x4 accA[2][4], accB[2][4];    // [fi: iLo/iHi][fu: 0,1 even-u | 2,3 odd-u]
    {
        #pragma unroll
        for (int fi = 0; fi < 2; ++fi)
            #pragma unroll
            for (int fu = 0; fu < 4; ++fu) {
                accA[fi][fu] = (f32x4){0.f, 0.f, 0.f, 0.f};
                accB[fi][fu] = (f32x4){0.f, 0.f, 0.f, 0.f};
            }
        #pragma unroll
        for (int t = 0; t < 4; ++t) {
            const int j0 = ((t + wst) & 3) * 32;
            // fold (f32, exact) + convert; pairwise so raw regs die early
            pk8 xeL, xoL, xeH, xoH;
            {
                f32x4 e = r0 + r2, o = r0 - r2;
                xeL.u[0] = cvtpk(e[0], e[1]); xeL.u[1] = cvtpk(e[2], e[3]);
                xoL.u[0] = cvtpk(o[0], o[1]); xoL.u[1] = cvtpk(o[2], o[3]);
            }
            {
                f32x4 e = r1 + r3, o = r1 - r3;
                xeL.u[2] = cvtpk(e[0], e[1]); xeL.u[3] = cvtpk(e[2], e[3]);
                xoL.u[2] = cvtpk(o[0], o[1]); xoL.u[3] = cvtpk(o[2], o[3]);
            }
            {
                f32x4 e = r4 + r6, o = r4 - r6;
                xeH.u[0] = cvtpk(e[0], e[1]); xeH.u[1] = cvtpk(e[2], e[3]);
                xoH.u[0] = cvtpk(o[0], o[1]); xoH.u[1] = cvtpk(o[2], o[3]);
            }
            {
                f32x4 e = r5 + r7, o = r5 - r7;
                xeH.u[2] = cvtpk(e[0], e[1]); xeH.u[3] = cvtpk(e[2], e[3]);
                xoH.u[2] = cvtpk(o[0], o[1]); xoH.u[3] = cvtpk(o[2], o[3]);
            }
            short8 XE0 = xeL.s8, XO0 = xoL.s8, XE1 = xeH.s8, XO1 = xoH.s8;
            // batch 1: issue next tile's iLo loads
            if (t < 3) {
                const int jn = ((t + 1 + wst) & 3) * 32;
                r0 = *(const f32x4*)(xL + jn);       r1 = *(const f32x4*)(xL + jn + 4);
                r2 = *(const f32x4*)(xL + jn + 128); r3 = *(const f32x4*)(xL + jn + 132);
            }
            // even-u tables + MFMA
            short8 ca0, ca1, sa0, sa1;
            {
                int row = l15;
                int byte = row * 256 + (((j0 + lk8) * 2) ^ ((row & 7) << 4));
                ca0 = *(const short8*)(lds + byte);
                sa0 = *(const short8*)(lds + 16384 + byte);
            }
            {
                int row = 16 + l15;
                int byte = row * 256 + (((j0 + lk8) * 2) ^ ((row & 7) << 4));
                ca1 = *(const short8*)(lds + byte);
                sa1 = *(const short8*)(lds + 16384 + byte);
            }
            __builtin_amdgcn_s_setprio(1);
            accA[0][0] = MFMA(XE0, ca0, accA[0][0]); accA[1][0] = MFMA(XE1, ca0, accA[1][0]);
            accB[0][0] = MFMA(XE0, sa0, accB[0][0]); accB[1][0] = MFMA(XE1, sa0, accB[1][0]);
            accA[0][1] = MFMA(XE0, ca1, accA[0][1]); accA[1][1] = MFMA(XE1, ca1, accA[1][1]);
            accB[0][1] = MFMA(XE0, sa1, accB[0][1]); accB[1][1] = MFMA(XE1, sa1, accB[1][1]);
            __builtin_amdgcn_s_setprio(0);
            // batch 2: issue next tile's iHi loads
            if (t < 3) {
                const int jn = ((t + 1 + wst) & 3) * 32;
                r4 = *(const f32x4*)(xH + jn);       r5 = *(const f32x4*)(xH + jn + 4);
                r6 = *(const f32x4*)(xH + jn + 128); r7 = *(const f32x4*)(xH + jn + 132);
            }
            // odd-u tables + MFMA
            short8 ca2, ca3, sa2, sa3;
            {
                int row = 32 + l15;
                int byte = row * 256 + (((j0 + lk8) * 2) ^ ((row & 7) << 4));
                ca2 = *(const short8*)(lds + byte);
                sa2 = *(const short8*)(lds + 16384 + byte);
            }
            {
                int row = 48 + l15;
                int byte = row * 256 + (((j0 + lk8) * 2) ^ ((row & 7) << 4));
                ca3 = *(const short8*)(lds + byte);
                sa3 = *(const short8*)(lds + 16384 + byte);
            }
            __builtin_amdgcn_s_setprio(1);
            accA[0][2] = MFMA(XO0, ca2, accA[0][2]); accA[1][2] = MFMA(XO1, ca2, accA[1][2]);
            accB[0][2] = MFMA(XO0, sa2, accB[0][2]); accB[1][2] = MFMA(XO1, sa2, accB[1][2]);
            accA[0][3] = MFMA(XO0, ca3, accA[0][3]); accA[1][3] = MFMA(XO1, ca3, accA[1][3]);
            accB[0][3] = MFMA(XO0, sa3, accB[0][3]); accB[1][3] = MFMA(XO1, sa3, accB[1][3]);
            __builtin_amdgcn_s_setprio(0);
        }
    }
    __syncthreads();   // all table reads done; LDS region can be overwritten

    // ---- HOISTED phase-D table prologue: issue before phase C (LDS-independent) ---
    const int wu = wave >> 2;        // 0..1 : u-slice of 32
    const int vt = wave & 3;         // 0..3 : v-slice of 32 (16 even + 16 odd)
    const short* __restrict__ pcE = gcE + (vt * 16 + l15) * 128 + lk8;
    const short* __restrict__ pcO = gcO + (vt * 16 + l15) * 128 + lk8;
    const short* __restrict__ psE = gsE + (vt * 16 + l15) * 128 + lk8;
    const short* __restrict__ psO = gsO + (vt * 16 + l15) * 128 + lk8;
    const int iA = (wst & 3) * 32;
    const int iB = ((wst + 1) & 3) * 32;
    short8 AcE = *(const short8*)(pcE + iA), AcO = *(const short8*)(pcO + iA);
    short8 AsE = *(const short8*)(psE + iA), AsO = *(const short8*)(psO + iA);
    short8 BcE = *(const short8*)(pcE + iB), BcO = *(const short8*)(pcO + iB);
    short8 BsE = *(const short8*)(psE + iB), BsO = *(const short8*)(psO + iB);

    // ------ phase C: i-fold on f32 acc (e=lo+hi, o=lo-hi), b64 writes swizzled ------
    {
        const int kb = wave * 16 + lr4;              // folded i-slot base (4 consec)
        #pragma unroll
        for (int fu = 0; fu < 4; ++fu) {
            f32x4 eA = accA[0][fu] + accA[1][fu];
            f32x4 oA = accA[0][fu] - accA[1][fu];
            f32x4 eB = accB[0][fu] + accB[1][fu];
            f32x4 oB = accB[0][fu] - accB[1][fu];
            int ul  = 2 * ((fu & 1) * 16 + l15) + (fu >> 1);   // u row 0..63
            int sw  = SWZ(ul);
            int byE = ul * 512 + ((kb * 2) ^ sw);
            int byO = ul * 512 + (((kb + 128) * 2) ^ sw);
            pk4 ea, oa, eb, ob;
            ea.u[0] = cvtpk(eA[0], eA[1]); ea.u[1] = cvtpk(eA[2], eA[3]);
            oa.u[0] = cvtpk(oA[0], oA[1]); oa.u[1] = cvtpk(oA[2], oA[3]);
            eb.u[0] = cvtpk(eB[0], eB[1]); eb.u[1] = cvtpk(eB[2], eB[3]);
            ob.u[0] = cvtpk(oB[0], oB[1]); ob.u[1] = cvtpk(oB[2], oB[3]);
            *(bf16x4*)(lds + byE)         = ea.s4;
            *(bf16x4*)(lds + byO)         = oa.s4;
            *(bf16x4*)(lds + 32768 + byE) = eb.s4;
            *(bf16x4*)(lds + 32768 + byO) = ob.s4;
        }
    }
    __syncthreads();

    // -------- phase D: stage 2, K=128 folded, parity tables, 2-deep prefetch -------
    {
        f32x4 accRE[2], accRO[2], accIE[2], accIO[2];
        #pragma unroll
        for (int fu = 0; fu < 2; ++fu) {
            accRE[fu] = (f32x4){0.f, 0.f, 0.f, 0.f};
            accRO[fu] = (f32x4){0.f, 0.f, 0.f, 0.f};
            accIE[fu] = (f32x4){0.f, 0.f, 0.f, 0.f};
            accIO[fu] = (f32x4){0.f, 0.f, 0.f, 0.f};
        }
        #pragma unroll
        for (int t = 0; t < 4; ++t) {
            const int is = ((t + wst) & 3) * 32;
            short8 cE = AcE, cO = AcO, sE = AsE, sO = AsO;
            AcE = BcE; AcO = BcO; AsE = BsE; AsO = BsO;
            if (t < 2) {   // issue tile t+2
                const int in = ((t + 2 + wst) & 3) * 32;
                BcE = *(const short8*)(pcE + in); BcO = *(const short8*)(pcO + in);
                BsE = *(const short8*)(psE + in); BsO = *(const short8*)(psO + in);
            }
            short8 sEn = sE ^ smask;
            short8 sOn = sO ^ smask;
            short8 eA[2], oA[2], eB[2], oB[2];
            #pragma unroll
            for (int fu = 0; fu < 2; ++fu) {
                int ul  = wu * 32 + fu * 16 + l15;
                int sw  = SWZ(ul);
                int byE = ul * 512 + (((is + lk8) * 2) ^ sw);
                int byO = ul * 512 + (((is + 128 + lk8) * 2) ^ sw);
                eA[fu] = *(const short8*)(lds + byE);
                oA[fu] = *(const short8*)(lds + byO);
                eB[fu] = *(const short8*)(lds + 32768 + byE);
                oB[fu] = *(const short8*)(lds + 32768 + byO);
            }
            __builtin_amdgcn_s_setprio(1);
            // 8 independent accs first:
            accRE[0] = MFMA(eA[0], cE, accRE[0]); accRE[1] = MFMA(eA[1], cE, accRE[1]);
            accRO[0] = MFMA(oA[0], cO, accRO[0]); accRO[1] = MFMA(oA[1], cO, accRO[1]);
            accIE[0] = MFMA(eB[0], cE, accIE[0]); accIE[1] = MFMA(eB[1], cE, accIE[1]);
            accIO[0] = MFMA(oB[0], cO, accIO[0]); accIO[1] = MFMA(oB[1], cO, accIO[1]);
            // dependent set, distance 8:
            accRE[0] = MFMA(eB[0], sE, accRE[0]); accRE[1] = MFMA(eB[1], sE, accRE[1]);
            accRO[0] = MFMA(oB[0], sO, accRO[0]); accRO[1] = MFMA(oB[1], sO, accRO[1]);
            accIE[0] = MFMA(eA[0], sEn, accIE[0]); accIE[1] = MFMA(eA[1], sEn, accIE[1]);
            accIO[0] = MFMA(oA[0], sOn, accIO[0]); accIO[1] = MFMA(oA[1], sOn, accIO[1]);
            __builtin_amdgcn_s_setprio(0);
        }
        #pragma unroll
        for (int fu = 0; fu < 2; ++fu)
            #pragma unroll
            for (int r = 0; r < 4; ++r) {
                int u = h * 64 + wu * 32 + fu * 16 + lr4 + r;
                int v = vt * 32 + 2 * l15;            // even/odd interleave
                f32x2 vr = {accRE[fu][r], accRO[fu][r]};
                f32x2 vi = {accIE[fu][r], accIO[fu][r]};
                *(f32x2*)(outR + u * KF + v) = vr;
                *(f32x2*)(outI + u * KF + v) = vi;
            }
    }
}

extern "C" void kernel_launch(void* const* d_in, const int* in_sizes, int n_in,
                              void* d_out, int out_size, void* d_ws, size_t ws_size,
                              hipStream_t stream) {
    const float* x = (const float*)d_in[0];
    float* out = (float*)d_out;
    gen_tables<<<dim3(32), dim3(256), 0, stream>>>();
    freq_dft<<<dim3(NIMG * 2), dim3(512), 0, stream>>>(x, out);
}

// Round 13
// 137.433 us; speedup vs baseline: 1.1359x; 1.1359x over previous
//
#include <hip/hip_runtime.h>
#include <hip/hip_bf16.h>

// FrequencyLayer: separable real DFT via bf16 MFMA.
// real[b,c,u,v] = sum_{i,j} x[i,j] cos(2pi(j*u+i*v)/N)
// imag[b,c,u,v] = -sum_{i,j} x[i,j] sin(-... )  (see ref), N=256, u,v in [0,128)
//
// v13 = v11 (134us) + SWZ conflict fix ONLY (v12's A/B isolated setprio as the
// regressor: it desynced the XCD-paired blocks' X streams, FETCH 132->177MB;
// SWZ itself cut SQ_LDS_BANK_CONFLICT 7.34M->5.24M as predicted).
//  - intermediate-region swizzle: sw = ((ul&7)<<4) ^ ((ul&8)<<1) — spreads
//    phase-C's even-row writes over all 8 bank groups (was 4-way conflicted);
//    phase-D reads stay 2-way. Applied to writer AND reader. NO setprio.

typedef __attribute__((ext_vector_type(8))) short short8;   // 8 bf16 = 4 VGPR
typedef __attribute__((ext_vector_type(4))) short bf16x4;   // 4 bf16 = 8B
typedef __attribute__((ext_vector_type(4))) float f32x4;    // MFMA C/D frag
typedef __attribute__((ext_vector_type(2))) float f32x2;

typedef union { short8 s8; unsigned u[4]; } pk8;            // v9-proven pattern
typedef union { bf16x4 s4; unsigned u[2]; } pk4;

#define NN 256
#define KF 128
#define NIMG 1024

// unified parity tables, rows m=0..63 -> freq 2m (E) / 2m+1 (O); cols j=0..127
__device__ __align__(16) short gcE[64 * 128];
__device__ __align__(16) short gcO[64 * 128];
__device__ __align__(16) short gsE[64 * 128];
__device__ __align__(16) short gsO[64 * 128];
__device__ int g_tables_done = 0;

__device__ __forceinline__ short f2bf(float f) {
    union { float f; unsigned u; } v; v.f = f;
    unsigned r = v.u + 0x7FFFu + ((v.u >> 16) & 1u);  // RNE
    return (short)(r >> 16);
}

__device__ __forceinline__ unsigned cvtpk(float lo, float hi) {
    unsigned r;
    asm("v_cvt_pk_bf16_f32 %0, %1, %2" : "=v"(r) : "v"(lo), "v"(hi));
    return r;
}

__global__ void gen_tables() {
    if (g_tables_done) return;           // tables persist across iterations
    int tid = blockIdx.x * blockDim.x + threadIdx.x;
    if (tid < 64 * 128) {
        const float w = 0.02454369260617026f;            // 2pi/256
        int m = tid >> 7;
        int j = tid & 127;
        int pe = (j * (2 * m)) & 255;
        int po = (j * (2 * m + 1)) & 255;
        float se, ce, so, co;
        sincosf((float)pe * w, &se, &ce);
        sincosf((float)po * w, &so, &co);
        gcE[tid] = f2bf(ce);
        gcO[tid] = f2bf(co);
        gsE[tid] = f2bf(se);
        gsO[tid] = f2bf(so);
    }
    __threadfence();
    if (tid == 0) g_tables_done = 1;     // set AFTER writes are visible
}

#define MFMA(a, b, c) __builtin_amdgcn_mfma_f32_16x16x32_bf16(a, b, c, 0, 0, 0)
// swizzle for the 512B-row intermediate region (phase C writes / phase D reads)
#define SWZ(ul) ((((ul) & 7) << 4) ^ (((ul) & 8) << 1))

__global__ __launch_bounds__(512, 4) void freq_dft(const float* __restrict__ x,
                                                   float* __restrict__ out) {
    // LDS (64KB), two lifetimes:
    //   phase A/B: Ctab [64][128] bf16 swz (16KB) @0 | Stab (-sin, 16KB) @16384
    //   phase C/D: eA|oA [64u][256k] (32KB) @0 | eBn|oBn (32KB) @32768
    __shared__ __align__(16) char lds[65536];

    // XCD-pairing decode: both h-half blocks of one image land on the same XCD.
    const int bid = blockIdx.x;
    const int cc  = bid & 7;
    const int q   = bid >> 3;
    const int h   = q & 1;
    const int img = cc + ((q >> 1) << 3);

    const float* __restrict__ X = x + (size_t)img * (NN * NN);
    float* __restrict__ outR = out + (size_t)img * (KF * KF);
    float* __restrict__ outI = outR + (size_t)NIMG * (KF * KF);

    const int lane = threadIdx.x & 63;
    const int wave = threadIdx.x >> 6;   // 0..7
    const int l15  = lane & 15;
    const int lk8  = (lane >> 4) << 3;   // A/B frag k-base (elems)
    const int lr4  = (lane >> 4) << 2;   // D frag row-base
    const int wst  = wave;               // stagger offset

    const short8 smask = {(short)0x8000, (short)0x8000, (short)0x8000, (short)0x8000,
                          (short)0x8000, (short)0x8000, (short)0x8000, (short)0x8000};

    // ---- HOISTED phase-B X prologue: issue before phase A (LDS-independent) -------
    const int i0 = wave * 16;
    const float* __restrict__ xL = X + (i0 + l15) * NN + lk8;        // iLo rows
    const float* __restrict__ xH = X + (i0 + 128 + l15) * NN + lk8;  // iHi rows
    const int jP = (wst & 3) * 32;
    f32x4 r0 = *(const f32x4*)(xL + jP),       r1 = *(const f32x4*)(xL + jP + 4);
    f32x4 r2 = *(const f32x4*)(xL + jP + 128), r3 = *(const f32x4*)(xL + jP + 132);
    f32x4 r4 = *(const f32x4*)(xH + jP),       r5 = *(const f32x4*)(xH + jP + 4);
    f32x4 r6 = *(const f32x4*)(xH + jP + 128), r7 = *(const f32x4*)(xH + jP + 132);

    // ---------------- phase A: parity tables -> LDS (swizzled; sin negated) --------
    {
        #pragma unroll
        for (int k = 0; k < 2; ++k) {      // Ctab: 1024 x 16B chunks
            int c   = threadIdx.x + k * 512;
            int row = c >> 4, chk = c & 15;
            int byte = row * 256 + ((chk << 4) ^ ((row & 7) << 4));
            const short* src = (row < 32 ? gcE + (h * 32 + row) * 128
                                         : gcO + (h * 32 + row - 32) * 128) + chk * 8;
            *(short8*)(lds + byte) = *(const short8*)src;
        }
        #pragma unroll
        for (int k = 0; k < 2; ++k) {      // Stab = -sin
            int c   = threadIdx.x + k * 512;
            int row = c >> 4, chk = c & 15;
            int byte = row * 256 + ((chk << 4) ^ ((row & 7) << 4));
            const short* src = (row < 32 ? gsE + (h * 32 + row) * 128
                                         : gsO + (h * 32 + row - 32) * 128) + chk * 8;
            short8 v = *(const short8*)src;
            *(short8*)(lds + 16384 + byte) = v ^ smask;
        }
    }
    __syncthreads();

    // ------- phase B: stage 1, K=128 j-folded, parity tables from LDS --------------
    f32x4 accA[2][4], accB[2][4];    // [fi: iLo/iHi][fu: 0,1 even-u | 2,3 odd-u]
    {
        #pragma unroll
        for (int fi = 0; fi < 2; ++fi)
            #pragma unroll
            for (int fu = 0; fu < 4; ++fu) {
                accA[fi][fu] = (f32x4){0.f, 0.f, 0.f, 0.f};
                accB[fi][fu] = (f32x4){0.f, 0.f, 0.f, 0.f};
            }
        #pragma unroll
        for (int t = 0; t < 4; ++t) {
            const int j0 = ((t + wst) & 3) * 32;
            // fold (f32, exact) + convert; pairwise so raw regs die early
            pk8 xeL, xoL, xeH, xoH;
            {
                f32x4 e = r0 + r2, o = r0 - r2;
                xeL.u[0] = cvtpk(e[0], e[1]); xeL.u[1] = cvtpk(e[2], e[3]);
                xoL.u[0] = cvtpk(o[0], o[1]); xoL.u[1] = cvtpk(o[2], o[3]);
            }
            {
                f32x4 e = r1 + r3, o = r1 - r3;
                xeL.u[2] = cvtpk(e[0], e[1]); xeL.u[3] = cvtpk(e[2], e[3]);
                xoL.u[2] = cvtpk(o[0], o[1]); xoL.u[3] = cvtpk(o[2], o[3]);
            }
            {
                f32x4 e = r4 + r6, o = r4 - r6;
                xeH.u[0] = cvtpk(e[0], e[1]); xeH.u[1] = cvtpk(e[2], e[3]);
                xoH.u[0] = cvtpk(o[0], o[1]); xoH.u[1] = cvtpk(o[2], o[3]);
            }
            {
                f32x4 e = r5 + r7, o = r5 - r7;
                xeH.u[2] = cvtpk(e[0], e[1]); xeH.u[3] = cvtpk(e[2], e[3]);
                xoH.u[2] = cvtpk(o[0], o[1]); xoH.u[3] = cvtpk(o[2], o[3]);
            }
            short8 XE0 = xeL.s8, XO0 = xoL.s8, XE1 = xeH.s8, XO1 = xoH.s8;
            // batch 1: issue next tile's iLo loads
            if (t < 3) {
                const int jn = ((t + 1 + wst) & 3) * 32;
                r0 = *(const f32x4*)(xL + jn);       r1 = *(const f32x4*)(xL + jn + 4);
                r2 = *(const f32x4*)(xL + jn + 128); r3 = *(const f32x4*)(xL + jn + 132);
            }
            // even-u tables + MFMA
            short8 ca0, ca1, sa0, sa1;
            {
                int row = l15;
                int byte = row * 256 + (((j0 + lk8) * 2) ^ ((row & 7) << 4));
                ca0 = *(const short8*)(lds + byte);
                sa0 = *(const short8*)(lds + 16384 + byte);
            }
            {
                int row = 16 + l15;
                int byte = row * 256 + (((j0 + lk8) * 2) ^ ((row & 7) << 4));
                ca1 = *(const short8*)(lds + byte);
                sa1 = *(const short8*)(lds + 16384 + byte);
            }
            accA[0][0] = MFMA(XE0, ca0, accA[0][0]); accA[1][0] = MFMA(XE1, ca0, accA[1][0]);
            accB[0][0] = MFMA(XE0, sa0, accB[0][0]); accB[1][0] = MFMA(XE1, sa0, accB[1][0]);
            accA[0][1] = MFMA(XE0, ca1, accA[0][1]); accA[1][1] = MFMA(XE1, ca1, accA[1][1]);
            accB[0][1] = MFMA(XE0, sa1, accB[0][1]); accB[1][1] = MFMA(XE1, sa1, accB[1][1]);
            // batch 2: issue next tile's iHi loads
            if (t < 3) {
                const int jn = ((t + 1 + wst) & 3) * 32;
                r4 = *(const f32x4*)(xH + jn);       r5 = *(const f32x4*)(xH + jn + 4);
                r6 = *(const f32x4*)(xH + jn + 128); r7 = *(const f32x4*)(xH + jn + 132);
            }
            // odd-u tables + MFMA
            short8 ca2, ca3, sa2, sa3;
            {
                int row = 32 + l15;
                int byte = row * 256 + (((j0 + lk8) * 2) ^ ((row & 7) << 4));
                ca2 = *(const short8*)(lds + byte);
                sa2 = *(const short8*)(lds + 16384 + byte);
            }
            {
                int row = 48 + l15;
                int byte = row * 256 + (((j0 + lk8) * 2) ^ ((row & 7) << 4));
                ca3 = *(const short8*)(lds + byte);
                sa3 = *(const short8*)(lds + 16384 + byte);
            }
            accA[0][2] = MFMA(XO0, ca2, accA[0][2]); accA[1][2] = MFMA(XO1, ca2, accA[1][2]);
            accB[0][2] = MFMA(XO0, sa2, accB[0][2]); accB[1][2] = MFMA(XO1, sa2, accB[1][2]);
            accA[0][3] = MFMA(XO0, ca3, accA[0][3]); accA[1][3] = MFMA(XO1, ca3, accA[1][3]);
            accB[0][3] = MFMA(XO0, sa3, accB[0][3]); accB[1][3] = MFMA(XO1, sa3, accB[1][3]);
        }
    }
    __syncthreads();   // all table reads done; LDS region can be overwritten

    // ---- HOISTED phase-D table prologue: issue before phase C (LDS-independent) ---
    const int wu = wave >> 2;        // 0..1 : u-slice of 32
    const int vt = wave & 3;         // 0..3 : v-slice of 32 (16 even + 16 odd)
    const short* __restrict__ pcE = gcE + (vt * 16 + l15) * 128 + lk8;
    const short* __restrict__ pcO = gcO + (vt * 16 + l15) * 128 + lk8;
    const short* __restrict__ psE = gsE + (vt * 16 + l15) * 128 + lk8;
    const short* __restrict__ psO = gsO + (vt * 16 + l15) * 128 + lk8;
    const int iA = (wst & 3) * 32;
    const int iB = ((wst + 1) & 3) * 32;
    short8 AcE = *(const short8*)(pcE + iA), AcO = *(const short8*)(pcO + iA);
    short8 AsE = *(const short8*)(psE + iA), AsO = *(const short8*)(psO + iA);
    short8 BcE = *(const short8*)(pcE + iB), BcO = *(const short8*)(pcO + iB);
    short8 BsE = *(const short8*)(psE + iB), BsO = *(const short8*)(psO + iB);

    // ------ phase C: i-fold on f32 acc (e=lo+hi, o=lo-hi), b64 writes swizzled ------
    {
        const int kb = wave * 16 + lr4;              // folded i-slot base (4 consec)
        #pragma unroll
        for (int fu = 0; fu < 4; ++fu) {
            f32x4 eA = accA[0][fu] + accA[1][fu];
            f32x4 oA = accA[0][fu] - accA[1][fu];
            f32x4 eB = accB[0][fu] + accB[1][fu];
            f32x4 oB = accB[0][fu] - accB[1][fu];
            int ul  = 2 * ((fu & 1) * 16 + l15) + (fu >> 1);   // u row 0..63
            int sw  = SWZ(ul);
            int byE = ul * 512 + ((kb * 2) ^ sw);
            int byO = ul * 512 + (((kb + 128) * 2) ^ sw);
            pk4 ea, oa, eb, ob;
            ea.u[0] = cvtpk(eA[0], eA[1]); ea.u[1] = cvtpk(eA[2], eA[3]);
            oa.u[0] = cvtpk(oA[0], oA[1]); oa.u[1] = cvtpk(oA[2], oA[3]);
            eb.u[0] = cvtpk(eB[0], eB[1]); eb.u[1] = cvtpk(eB[2], eB[3]);
            ob.u[0] = cvtpk(oB[0], oB[1]); ob.u[1] = cvtpk(oB[2], oB[3]);
            *(bf16x4*)(lds + byE)         = ea.s4;
            *(bf16x4*)(lds + byO)         = oa.s4;
            *(bf16x4*)(lds + 32768 + byE) = eb.s4;
            *(bf16x4*)(lds + 32768 + byO) = ob.s4;
        }
    }
    __syncthreads();

    // -------- phase D: stage 2, K=128 folded, parity tables, 2-deep prefetch -------
    {
        f32x4 accRE[2], accRO[2], accIE[2], accIO[2];
        #pragma unroll
        for (int fu = 0; fu < 2; ++fu) {
            accRE[fu] = (f32x4){0.f, 0.f, 0.f, 0.f};
            accRO[fu] = (f32x4){0.f, 0.f, 0.f, 0.f};
            accIE[fu] = (f32x4){0.f, 0.f, 0.f, 0.f};
            accIO[fu] = (f32x4){0.f, 0.f, 0.f, 0.f};
        }
        #pragma unroll
        for (int t = 0; t < 4; ++t) {
            const int is = ((t + wst) & 3) * 32;
            short8 cE = AcE, cO = AcO, sE = AsE, sO = AsO;
            AcE = BcE; AcO = BcO; AsE = BsE; AsO = BsO;
            if (t < 2) {   // issue tile t+2
                const int in = ((t + 2 + wst) & 3) * 32;
                BcE = *(const short8*)(pcE + in); BcO = *(const short8*)(pcO + in);
                BsE = *(const short8*)(psE + in); BsO = *(const short8*)(psO + in);
            }
            short8 sEn = sE ^ smask;
            short8 sOn = sO ^ smask;
            short8 eA[2], oA[2], eB[2], oB[2];
            #pragma unroll
            for (int fu = 0; fu < 2; ++fu) {
                int ul  = wu * 32 + fu * 16 + l15;
                int sw  = SWZ(ul);
                int byE = ul * 512 + (((is + lk8) * 2) ^ sw);
                int byO = ul * 512 + (((is + 128 + lk8) * 2) ^ sw);
                eA[fu] = *(const short8*)(lds + byE);
                oA[fu] = *(const short8*)(lds + byO);
                eB[fu] = *(const short8*)(lds + 32768 + byE);
                oB[fu] = *(const short8*)(lds + 32768 + byO);
            }
            // 8 independent accs first:
            accRE[0] = MFMA(eA[0], cE, accRE[0]); accRE[1] = MFMA(eA[1], cE, accRE[1]);
            accRO[0] = MFMA(oA[0], cO, accRO[0]); accRO[1] = MFMA(oA[1], cO, accRO[1]);
            accIE[0] = MFMA(eB[0], cE, accIE[0]); accIE[1] = MFMA(eB[1], cE, accIE[1]);
            accIO[0] = MFMA(oB[0], cO, accIO[0]); accIO[1] = MFMA(oB[1], cO, accIO[1]);
            // dependent set, distance 8:
            accRE[0] = MFMA(eB[0], sE, accRE[0]); accRE[1] = MFMA(eB[1], sE, accRE[1]);
            accRO[0] = MFMA(oB[0], sO, accRO[0]); accRO[1] = MFMA(oB[1], sO, accRO[1]);
            accIE[0] = MFMA(eA[0], sEn, accIE[0]); accIE[1] = MFMA(eA[1], sEn, accIE[1]);
            accIO[0] = MFMA(oA[0], sOn, accIO[0]); accIO[1] = MFMA(oA[1], sOn, accIO[1]);
        }
        #pragma unroll
        for (int fu = 0; fu < 2; ++fu)
            #pragma unroll
            for (int r = 0; r < 4; ++r) {
                int u = h * 64 + wu * 32 + fu * 16 + lr4 + r;
                int v = vt * 32 + 2 * l15;            // even/odd interleave
                f32x2 vr = {accRE[fu][r], accRO[fu][r]};
                f32x2 vi = {accIE[fu][r], accIO[fu][r]};
                *(f32x2*)(outR + u * KF + v) = vr;
                *(f32x2*)(outI + u * KF + v) = vi;
            }
    }
}

extern "C" void kernel_launch(void* const* d_in, const int* in_sizes, int n_in,
                              void* d_out, int out_size, void* d_ws, size_t ws_size,
                              hipStream_t stream) {
    const float* x = (const float*)d_in[0];
    float* out = (float*)d_out;
    gen_tables<<<dim3(32), dim3(256), 0, stream>>>();
    freq_dft<<<dim3(NIMG * 2), dim3(512), 0, stream>>>(x, out);
}

// Round 14
// 134.026 us; speedup vs baseline: 1.1648x; 1.0254x over previous
//
#include <hip/hip_runtime.h>
#include <hip/hip_bf16.h>

// FrequencyLayer: separable real DFT via bf16 MFMA.
// real[b,c,u,v] = sum_{i,j} x[i,j] cos(2pi(j*u+i*v)/N)
// imag[b,c,u,v] = -sum_{i,j} x[i,j] sin(2pi(j*u+i*v)/N), N=256, u,v in [0,128)
//
// v14 = exact revert to v10 (champion, 133.97us bench). Ledger of exonerated
// levers (all counter-verified A/B): occupancy up/down, barrier removal,
// prefetch depth, work-halving (v10: MFMA work -50% -> time flat), hoisting,
// setprio (-14%, breaks XCD-paired X-stream dedup), bank-conflict swizzle
// (conflicts -29%, time -2%). Floor cause: per-wave latency chains at the
// 128-reg/wave cliff (64 acc + 64 arch); >16 waves/CU is register-infeasible
// in every partitioning (u-quarter, merged-h, global-table, prefolded-X all
// land 100-136 regs/wave). Structure: dual parity-fold (j-fold in stage 1,
// i-fold in stage 2), unified 64x128 parity tables, XCD-paired h-blocks,
// wave-staggered 2-deep prefetch, cvt_pk conversions.

typedef __attribute__((ext_vector_type(8))) short short8;   // 8 bf16 = 4 VGPR
typedef __attribute__((ext_vector_type(4))) short bf16x4;   // 4 bf16 = 8B
typedef __attribute__((ext_vector_type(4))) float f32x4;    // MFMA C/D frag
typedef __attribute__((ext_vector_type(2))) float f32x2;

typedef union { short8 s8; unsigned u[4]; } pk8;            // v9-proven pattern
typedef union { bf16x4 s4; unsigned u[2]; } pk4;

#define NN 256
#define KF 128
#define NIMG 1024

// unified parity tables, rows m=0..63 -> freq 2m (E) / 2m+1 (O); cols j=0..127
__device__ __align__(16) short gcE[64 * 128];
__device__ __align__(16) short gcO[64 * 128];
__device__ __align__(16) short gsE[64 * 128];
__device__ __align__(16) short gsO[64 * 128];

__device__ __forceinline__ short f2bf(float f) {
    union { float f; unsigned u; } v; v.f = f;
    unsigned r = v.u + 0x7FFFu + ((v.u >> 16) & 1u);  // RNE
    return (short)(r >> 16);
}

__device__ __forceinline__ unsigned cvtpk(float lo, float hi) {
    unsigned r;
    asm("v_cvt_pk_bf16_f32 %0, %1, %2" : "=v"(r) : "v"(lo), "v"(hi));
    return r;
}

__global__ void gen_tables() {
    int tid = blockIdx.x * blockDim.x + threadIdx.x;
    if (tid >= 64 * 128) return;
    const float w = 0.02454369260617026f;            // 2pi/256
    int m = tid >> 7;
    int j = tid & 127;
    int pe = (j * (2 * m)) & 255;
    int po = (j * (2 * m + 1)) & 255;
    float se, ce, so, co;
    sincosf((float)pe * w, &se, &ce);
    sincosf((float)po * w, &so, &co);
    gcE[tid] = f2bf(ce);
    gcO[tid] = f2bf(co);
    gsE[tid] = f2bf(se);
    gsO[tid] = f2bf(so);
}

#define MFMA(a, b, c) __builtin_amdgcn_mfma_f32_16x16x32_bf16(a, b, c, 0, 0, 0)

__global__ __launch_bounds__(512, 4) void freq_dft(const float* __restrict__ x,
                                                   float* __restrict__ out) {
    // LDS (64KB), two lifetimes:
    //   phase A/B: Ctab [64][128] bf16 swz (16KB) @0 | Stab (-sin, 16KB) @16384
    //   phase C/D: eA|oA [64u][256k] (32KB) @0 | eBn|oBn (32KB) @32768
    __shared__ __align__(16) char lds[65536];

    // XCD-pairing decode: both h-half blocks of one image land on the same XCD.
    const int bid = blockIdx.x;
    const int cc  = bid & 7;
    const int q   = bid >> 3;
    const int h   = q & 1;
    const int img = cc + ((q >> 1) << 3);

    const float* __restrict__ X = x + (size_t)img * (NN * NN);
    float* __restrict__ outR = out + (size_t)img * (KF * KF);
    float* __restrict__ outI = outR + (size_t)NIMG * (KF * KF);

    const int lane = threadIdx.x & 63;
    const int wave = threadIdx.x >> 6;   // 0..7
    const int l15  = lane & 15;
    const int lk8  = (lane >> 4) << 3;   // A/B frag k-base (elems)
    const int lr4  = (lane >> 4) << 2;   // D frag row-base
    const int wst  = wave;               // stagger offset

    const short8 smask = {(short)0x8000, (short)0x8000, (short)0x8000, (short)0x8000,
                          (short)0x8000, (short)0x8000, (short)0x8000, (short)0x8000};

    // ---------------- phase A: parity tables -> LDS (swizzled; sin negated) --------
    {
        #pragma unroll
        for (int k = 0; k < 2; ++k) {      // Ctab: 1024 x 16B chunks
            int c   = threadIdx.x + k * 512;
            int row = c >> 4, chk = c & 15;
            int byte = row * 256 + ((chk << 4) ^ ((row & 7) << 4));
            const short* src = (row < 32 ? gcE + (h * 32 + row) * 128
                                         : gcO + (h * 32 + row - 32) * 128) + chk * 8;
            *(short8*)(lds + byte) = *(const short8*)src;
        }
        #pragma unroll
        for (int k = 0; k < 2; ++k) {      // Stab = -sin
            int c   = threadIdx.x + k * 512;
            int row = c >> 4, chk = c & 15;
            int byte = row * 256 + ((chk << 4) ^ ((row & 7) << 4));
            const short* src = (row < 32 ? gsE + (h * 32 + row) * 128
                                         : gsO + (h * 32 + row - 32) * 128) + chk * 8;
            short8 v = *(const short8*)src;
            *(short8*)(lds + 16384 + byte) = v ^ smask;
        }
    }
    __syncthreads();

    // ------- phase B: stage 1, K=128 j-folded, parity tables from LDS --------------
    f32x4 accA[2][4], accB[2][4];    // [fi: iLo/iHi][fu: 0,1 even-u | 2,3 odd-u]
    {
        const int i0 = wave * 16;
        #pragma unroll
        for (int fi = 0; fi < 2; ++fi)
            #pragma unroll
            for (int fu = 0; fu < 4; ++fu) {
                accA[fi][fu] = (f32x4){0.f, 0.f, 0.f, 0.f};
                accB[fi][fu] = (f32x4){0.f, 0.f, 0.f, 0.f};
            }
        const float* __restrict__ xL = X + (i0 + l15) * NN + lk8;        // iLo rows
        const float* __restrict__ xH = X + (i0 + 128 + l15) * NN + lk8;  // iHi rows
        const int jP = (wst & 3) * 32;
        f32x4 r0 = *(const f32x4*)(xL + jP),       r1 = *(const f32x4*)(xL + jP + 4);
        f32x4 r2 = *(const f32x4*)(xL + jP + 128), r3 = *(const f32x4*)(xL + jP + 132);
        f32x4 r4 = *(const f32x4*)(xH + jP),       r5 = *(const f32x4*)(xH + jP + 4);
        f32x4 r6 = *(const f32x4*)(xH + jP + 128), r7 = *(const f32x4*)(xH + jP + 132);
        #pragma unroll
        for (int t = 0; t < 4; ++t) {
            const int j0 = ((t + wst) & 3) * 32;
            // fold (f32, exact) + convert; pairwise so raw regs die early
            pk8 xeL, xoL, xeH, xoH;
            {
                f32x4 e = r0 + r2, o = r0 - r2;
                xeL.u[0] = cvtpk(e[0], e[1]); xeL.u[1] = cvtpk(e[2], e[3]);
                xoL.u[0] = cvtpk(o[0], o[1]); xoL.u[1] = cvtpk(o[2], o[3]);
            }
            {
                f32x4 e = r1 + r3, o = r1 - r3;
                xeL.u[2] = cvtpk(e[0], e[1]); xeL.u[3] = cvtpk(e[2], e[3]);
                xoL.u[2] = cvtpk(o[0], o[1]); xoL.u[3] = cvtpk(o[2], o[3]);
            }
            {
                f32x4 e = r4 + r6, o = r4 - r6;
                xeH.u[0] = cvtpk(e[0], e[1]); xeH.u[1] = cvtpk(e[2], e[3]);
                xoH.u[0] = cvtpk(o[0], o[1]); xoH.u[1] = cvtpk(o[2], o[3]);
            }
            {
                f32x4 e = r5 + r7, o = r5 - r7;
                xeH.u[2] = cvtpk(e[0], e[1]); xeH.u[3] = cvtpk(e[2], e[3]);
                xoH.u[2] = cvtpk(o[0], o[1]); xoH.u[3] = cvtpk(o[2], o[3]);
            }
            short8 XE0 = xeL.s8, XO0 = xoL.s8, XE1 = xeH.s8, XO1 = xoH.s8;
            // batch 1: issue next tile's iLo loads
            if (t < 3) {
                const int jn = ((t + 1 + wst) & 3) * 32;
                r0 = *(const f32x4*)(xL + jn);       r1 = *(const f32x4*)(xL + jn + 4);
                r2 = *(const f32x4*)(xL + jn + 128); r3 = *(const f32x4*)(xL + jn + 132);
            }
            // even-u tables + MFMA
            short8 ca0, ca1, sa0, sa1;
            {
                int row = l15;
                int byte = row * 256 + (((j0 + lk8) * 2) ^ ((row & 7) << 4));
                ca0 = *(const short8*)(lds + byte);
                sa0 = *(const short8*)(lds + 16384 + byte);
            }
            {
                int row = 16 + l15;
                int byte = row * 256 + (((j0 + lk8) * 2) ^ ((row & 7) << 4));
                ca1 = *(const short8*)(lds + byte);
                sa1 = *(const short8*)(lds + 16384 + byte);
            }
            accA[0][0] = MFMA(XE0, ca0, accA[0][0]); accA[1][0] = MFMA(XE1, ca0, accA[1][0]);
            accB[0][0] = MFMA(XE0, sa0, accB[0][0]); accB[1][0] = MFMA(XE1, sa0, accB[1][0]);
            accA[0][1] = MFMA(XE0, ca1, accA[0][1]); accA[1][1] = MFMA(XE1, ca1, accA[1][1]);
            accB[0][1] = MFMA(XE0, sa1, accB[0][1]); accB[1][1] = MFMA(XE1, sa1, accB[1][1]);
            // batch 2: issue next tile's iHi loads
            if (t < 3) {
                const int jn = ((t + 1 + wst) & 3) * 32;
                r4 = *(const f32x4*)(xH + jn);       r5 = *(const f32x4*)(xH + jn + 4);
                r6 = *(const f32x4*)(xH + jn + 128); r7 = *(const f32x4*)(xH + jn + 132);
            }
            // odd-u tables + MFMA
            short8 ca2, ca3, sa2, sa3;
            {
                int row = 32 + l15;
                int byte = row * 256 + (((j0 + lk8) * 2) ^ ((row & 7) << 4));
                ca2 = *(const short8*)(lds + byte);
                sa2 = *(const short8*)(lds + 16384 + byte);
            }
            {
                int row = 48 + l15;
                int byte = row * 256 + (((j0 + lk8) * 2) ^ ((row & 7) << 4));
                ca3 = *(const short8*)(lds + byte);
                sa3 = *(const short8*)(lds + 16384 + byte);
            }
            accA[0][2] = MFMA(XO0, ca2, accA[0][2]); accA[1][2] = MFMA(XO1, ca2, accA[1][2]);
            accB[0][2] = MFMA(XO0, sa2, accB[0][2]); accB[1][2] = MFMA(XO1, sa2, accB[1][2]);
            accA[0][3] = MFMA(XO0, ca3, accA[0][3]); accA[1][3] = MFMA(XO1, ca3, accA[1][3]);
            accB[0][3] = MFMA(XO0, sa3, accB[0][3]); accB[1][3] = MFMA(XO1, sa3, accB[1][3]);
        }
    }
    __syncthreads();   // all table reads done; LDS region can be overwritten

    // ------ phase C: i-fold on f32 acc (e=lo+hi, o=lo-hi), b64 writes swizzled ------
    {
        const int kb = wave * 16 + lr4;              // folded i-slot base (4 consec)
        #pragma unroll
        for (int fu = 0; fu < 4; ++fu) {
            f32x4 eA = accA[0][fu] + accA[1][fu];
            f32x4 oA = accA[0][fu] - accA[1][fu];
            f32x4 eB = accB[0][fu] + accB[1][fu];
            f32x4 oB = accB[0][fu] - accB[1][fu];
            int ul  = 2 * ((fu & 1) * 16 + l15) + (fu >> 1);   // u row 0..63
            int sw  = (ul & 7) << 4;
            int byE = ul * 512 + ((kb * 2) ^ sw);
            int byO = ul * 512 + (((kb + 128) * 2) ^ sw);
            pk4 ea, oa, eb, ob;
            ea.u[0] = cvtpk(eA[0], eA[1]); ea.u[1] = cvtpk(eA[2], eA[3]);
            oa.u[0] = cvtpk(oA[0], oA[1]); oa.u[1] = cvtpk(oA[2], oA[3]);
            eb.u[0] = cvtpk(eB[0], eB[1]); eb.u[1] = cvtpk(eB[2], eB[3]);
            ob.u[0] = cvtpk(oB[0], oB[1]); ob.u[1] = cvtpk(oB[2], oB[3]);
            *(bf16x4*)(lds + byE)         = ea.s4;
            *(bf16x4*)(lds + byO)         = oa.s4;
            *(bf16x4*)(lds + 32768 + byE) = eb.s4;
            *(bf16x4*)(lds + 32768 + byO) = ob.s4;
        }
    }
    __syncthreads();

    // -------- phase D: stage 2, K=128 folded, parity tables, 2-deep prefetch -------
    {
        const int wu = wave >> 2;        // 0..1 : u-slice of 32
        const int vt = wave & 3;         // 0..3 : v-slice of 32 (16 even + 16 odd)
        f32x4 accRE[2], accRO[2], accIE[2], accIO[2];
        #pragma unroll
        for (int fu = 0; fu < 2; ++fu) {
            accRE[fu] = (f32x4){0.f, 0.f, 0.f, 0.f};
            accRO[fu] = (f32x4){0.f, 0.f, 0.f, 0.f};
            accIE[fu] = (f32x4){0.f, 0.f, 0.f, 0.f};
            accIO[fu] = (f32x4){0.f, 0.f, 0.f, 0.f};
        }
        const short* __restrict__ pcE = gcE + (vt * 16 + l15) * 128 + lk8;
        const short* __restrict__ pcO = gcO + (vt * 16 + l15) * 128 + lk8;
        const short* __restrict__ psE = gsE + (vt * 16 + l15) * 128 + lk8;
        const short* __restrict__ psO = gsO + (vt * 16 + l15) * 128 + lk8;
        const int iA = (wst & 3) * 32;
        const int iB = ((wst + 1) & 3) * 32;
        short8 AcE = *(const short8*)(pcE + iA), AcO = *(const short8*)(pcO + iA);
        short8 AsE = *(const short8*)(psE + iA), AsO = *(const short8*)(psO + iA);
        short8 BcE = *(const short8*)(pcE + iB), BcO = *(const short8*)(pcO + iB);
        short8 BsE = *(const short8*)(psE + iB), BsO = *(const short8*)(psO + iB);
        #pragma unroll
        for (int t = 0; t < 4; ++t) {
            const int is = ((t + wst) & 3) * 32;
            short8 cE = AcE, cO = AcO, sE = AsE, sO = AsO;
            AcE = BcE; AcO = BcO; AsE = BsE; AsO = BsO;
            if (t < 2) {   // issue tile t+2
                const int in = ((t + 2 + wst) & 3) * 32;
                BcE = *(const short8*)(pcE + in); BcO = *(const short8*)(pcO + in);
                BsE = *(const short8*)(psE + in); BsO = *(const short8*)(psO + in);
            }
            short8 sEn = sE ^ smask;
            short8 sOn = sO ^ smask;
            short8 eA[2], oA[2], eB[2], oB[2];
            #pragma unroll
            for (int fu = 0; fu < 2; ++fu) {
                int ul  = wu * 32 + fu * 16 + l15;
                int sw  = (ul & 7) << 4;
                int byE = ul * 512 + (((is + lk8) * 2) ^ sw);
                int byO = ul * 512 + (((is + 128 + lk8) * 2) ^ sw);
                eA[fu] = *(const short8*)(lds + byE);
                oA[fu] = *(const short8*)(lds + byO);
                eB[fu] = *(const short8*)(lds + 32768 + byE);
                oB[fu] = *(const short8*)(lds + 32768 + byO);
            }
            // 8 independent accs first:
            accRE[0] = MFMA(eA[0], cE, accRE[0]); accRE[1] = MFMA(eA[1], cE, accRE[1]);
            accRO[0] = MFMA(oA[0], cO, accRO[0]); accRO[1] = MFMA(oA[1], cO, accRO[1]);
            accIE[0] = MFMA(eB[0], cE, accIE[0]); accIE[1] = MFMA(eB[1], cE, accIE[1]);
            accIO[0] = MFMA(oB[0], cO, accIO[0]); accIO[1] = MFMA(oB[1], cO, accIO[1]);
            // dependent set, distance 8:
            accRE[0] = MFMA(eB[0], sE, accRE[0]); accRE[1] = MFMA(eB[1], sE, accRE[1]);
            accRO[0] = MFMA(oB[0], sO, accRO[0]); accRO[1] = MFMA(oB[1], sO, accRO[1]);
            accIE[0] = MFMA(eA[0], sEn, accIE[0]); accIE[1] = MFMA(eA[1], sEn, accIE[1]);
            accIO[0] = MFMA(oA[0], sOn, accIO[0]); accIO[1] = MFMA(oA[1], sOn, accIO[1]);
        }
        #pragma unroll
        for (int fu = 0; fu < 2; ++fu)
            #pragma unroll
            for (int r = 0; r < 4; ++r) {
                int u = h * 64 + wu * 32 + fu * 16 + lr4 + r;
                int v = vt * 32 + 2 * l15;            // even/odd interleave
                f32x2 vr = {accRE[fu][r], accRO[fu][r]};
                f32x2 vi = {accIE[fu][r], accIO[fu][r]};
                *(f32x2*)(outR + u * KF + v) = vr;
                *(f32x2*)(outI + u * KF + v) = vi;
            }
    }
}

extern "C" void kernel_launch(void* const* d_in, const int* in_sizes, int n_in,
                              void* d_out, int out_size, void* d_ws, size_t ws_size,
                              hipStream_t stream) {
    const float* x = (const float*)d_in[0];
    float* out = (float*)d_out;
    gen_tables<<<dim3(32), dim3(256), 0, stream>>>();
    freq_dft<<<dim3(NIMG * 2), dim3(512), 0, stream>>>(x, out);
}